// Round 4
// baseline (40.049 us; speedup 1.0000x reference)
//
#include <hip/hip_runtime.h>

// ExodusNet: per-timestep 32-tap dense projection + LIF scan (membrane subtract).
// x: [N=16384, C=2, H=4, W=4, T=100] f32 (t innermost, chw stride = 100)
// W: [1,2,4,4] f32 (32 taps, uniform -> SGPRs)
// out: [N,1,1,1,T] f32 = spikes
//
// R1 38.7 / R2 37.3 (float2, 2 rounds, barriers) / R3 38.1 (float4 — reverted).
// R4: barrier-FREE per-wave pipeline. Every LDS buffer is produced and
// consumed by the same wave (in-order, lgkmcnt only), so no __syncthreads.
// 1024 persistent blocks (4/CU); each wave owns 4 neurons = 2 slabs of 2;
// slab k+1's loads are issued BEFORE slab k's scan+write-out, so the HBM
// read stream never pauses at phase boundaries.

#define T_STEPS 100
#define CHW     32
#define NPW     2        // neurons per wave per slab
#define SLABS   2        // slabs per wave -> 4 neurons/wave, 16/block
#define PITCH   102      // even -> 8B-aligned float2 rows; 102%32=6 offsets rows' banks

__global__ __launch_bounds__(256, 4)
void exodus_fused(const float* __restrict__ x,
                  const float* __restrict__ W,
                  float* __restrict__ out) {
    __shared__ float s_in[4][NPW][PITCH];        // per-wave private
    __shared__ float s_sp[4][NPW * T_STEPS];     // per-wave, flat 200 floats

    const int tid  = threadIdx.x;
    const int lane = tid & 63;
    const int wv   = tid >> 6;
    // first neuron owned by this wave
    const int wave_n0 = (blockIdx.x * 4 + wv) * (NPW * SLABS);
    const int NSTR = CHW * T_STEPS;              // 3200 floats per neuron

    float Wr[CHW];
    #pragma unroll
    for (int c = 0; c < CHW; ++c) Wr[c] = W[c];  // uniform -> scalar regs

    const bool ldr = (lane < T_STEPS / 2);       // 50 loader lanes, t = 2l, 2l+1

    float2 bA[16], bB[16];                       // double-buffered load chunks

    // ---- macros over the wave-private pipeline stages ----
#define ISSUE(buf, n_off, c_off)                                              \
    if (ldr) {                                                                \
        const float* xp = x + (size_t)(wave_n0 + (n_off)) * NSTR + 2 * lane;  \
        _Pragma("unroll")                                                     \
        for (int j = 0; j < 16; ++j)                                          \
            buf[j] = *reinterpret_cast<const float2*>(xp + ((c_off) + j) * T_STEPS); \
    }

#define CONSUME(buf, c_off, ax, ay)                                           \
    if (ldr) {                                                                \
        _Pragma("unroll")                                                     \
        for (int j = 0; j < 16; ++j) {                                        \
            ax = fmaf(Wr[(c_off) + j], buf[j].x, ax);                         \
            ay = fmaf(Wr[(c_off) + j], buf[j].y, ay);                         \
        }                                                                     \
    }

#define STORE_SIN(nl, ax, ay)                                                 \
    if (ldr) {                                                                \
        s_in[wv][nl][2 * lane]     = ax;                                      \
        s_in[wv][nl][2 * lane + 1] = ay;                                      \
    }

#define SCAN()                                                                \
    if (lane < NPW) {                                                         \
        const float* si = &s_in[wv][lane][0];                                 \
        float*       sp = &s_sp[wv][lane * T_STEPS];                          \
        const float A = 0.9048374180359595f;   /* exp(-1/10) as f32 */        \
        const float Bc = 0.0951625819640404f;  /* 1 - alpha */                \
        float v = 0.f;                                                        \
        _Pragma("unroll 4")                                                   \
        for (int t = 0; t < T_STEPS; ++t) {                                   \
            v = fmaf(A, v, Bc * si[t]);                                       \
            const float spk = (v >= 1.0f) ? 1.0f : 0.0f;                      \
            v -= spk;                          /* membrane subtract */        \
            sp[t] = spk;                                                      \
        }                                                                     \
    }

#define WRITEOUT(n_off)                                                       \
    if (ldr) {                                                                \
        const float4 r = *reinterpret_cast<const float4*>(&s_sp[wv][lane * 4]); \
        *reinterpret_cast<float4*>(                                           \
            out + (size_t)(wave_n0 + (n_off)) * T_STEPS + lane * 4) = r;      \
    }

    float n0x, n0y, n1x, n1y;

    // ================= slab 0: load + reduce (as R2) =================
    ISSUE(bA, 0, 0);  ISSUE(bB, 0, 16);
    n0x = n0y = 0.f;
    CONSUME(bA, 0, n0x, n0y);
    ISSUE(bA, 1, 0);
    CONSUME(bB, 16, n0x, n0y);  STORE_SIN(0, n0x, n0y);
    ISSUE(bB, 1, 16);
    n1x = n1y = 0.f;
    CONSUME(bA, 0, n1x, n1y);
    CONSUME(bB, 16, n1x, n1y);  STORE_SIN(1, n1x, n1y);

    // ============ prefetch slab 1's first 32 rows, then finish slab 0 ======
    ISSUE(bA, 2, 0);  ISSUE(bB, 2, 16);   // slab1 n0: in flight during scan
    SCAN();                                // slab 0 scan (lanes 0..1)
    WRITEOUT(0);                           // slab 0 write (800 B contiguous)

    // ============ slab 1: consume prefetched, keep issuing ============
    n0x = n0y = 0.f;
    CONSUME(bA, 0, n0x, n0y);
    ISSUE(bA, 3, 0);
    CONSUME(bB, 16, n0x, n0y);  STORE_SIN(0, n0x, n0y);
    ISSUE(bB, 3, 16);
    n1x = n1y = 0.f;
    CONSUME(bA, 0, n1x, n1y);
    CONSUME(bB, 16, n1x, n1y);  STORE_SIN(1, n1x, n1y);

    SCAN();                                // slab 1 scan
    WRITEOUT(NPW);                         // slab 1 write
}

extern "C" void kernel_launch(void* const* d_in, const int* in_sizes, int n_in,
                              void* d_out, int out_size, void* d_ws, size_t ws_size,
                              hipStream_t stream) {
    const float* x = (const float*)d_in[0];
    const float* W = (const float*)d_in[1];
    float* out = (float*)d_out;

    const int N = in_sizes[0] / (CHW * T_STEPS);   // 16384
    const int grid = N / (4 * NPW * SLABS);        // 1024 persistent blocks
    exodus_fused<<<grid, 256, 0, stream>>>(x, W, out);
}

// Round 5
// 37.636 us; speedup vs baseline: 1.0641x; 1.0641x over previous
//
#include <hip/hip_runtime.h>

// ExodusNet: per-timestep 32-tap dense projection + LIF scan (membrane subtract).
// x: [N=16384, C=2, H=4, W=4, T=100] f32 (t innermost, chw stride = 100)
// W: [1,2,4,4] f32 (32 taps, wave-uniform -> forced to SGPRs)
// out: [N,1,1,1,T] f32 = spikes
//
// R1 38.7 / R2 37.3 (float2+barriers, 4 blk/CU, 2 rounds) / R3 38.1 (float4,
// reverted) / R4 40.0 (barrier-free pipeline, reverted).
// R5: R2 structure, occupancy 4->8 blocks/CU. 2048 blocks = ONE round of
// 8/CU (32 waves/CU, max) -> no round-2 relaunch bubble; 7 sibling blocks'
// loads cover every scan/write window. To fit the 64-VGPR cap: load chunks
// 16->8 float2 (32 VGPR buffer), taps via readfirstlane -> SGPRs.

#define T_STEPS 100
#define CHW     32
#define NPW     2       // neurons per wave
#define NPB     8       // neurons per block (4 waves * NPW)
#define PITCH   101     // odd pitch -> <=2-way LDS bank aliasing (free)

__global__ __launch_bounds__(256, 8)
void exodus_fused(const float* __restrict__ x,
                  const float* __restrict__ W,
                  float* __restrict__ out) {
    __shared__ float s_in[NPB][PITCH];   // weighted input per (neuron, t)
    __shared__ float s_sp[NPB][PITCH];   // spikes per (neuron, t)

    const int tid    = threadIdx.x;
    const int lane   = tid & 63;
    const int wv     = tid >> 6;               // 0..3
    const int n_base = blockIdx.x * NPB;

    // 32 taps: wave-uniform -> pin to SGPRs (readfirstlane), so they don't
    // eat into the 64-VGPR budget at occupancy 8.
    float Wr[CHW];
    #pragma unroll
    for (int c = 0; c < CHW; ++c)
        Wr[c] = __int_as_float(__builtin_amdgcn_readfirstlane(__float_as_int(W[c])));

    // ---- Phase A: weighted[n][t] = sum_c W[c] * x[n][c][t] ----
    // lane l (<50) owns t = 2l, 2l+1. Per neuron: 32 float2 rows in 4 chunks
    // of 8, two register buffers, loads issued one chunk ahead of the FMAs.
    if (lane < T_STEPS / 2) {
        const float* xw = x + (size_t)(n_base + wv * NPW) * (CHW * T_STEPS) + 2 * lane;
        const int NSTR = CHW * T_STEPS;        // neuron stride in floats

        float2 bA[8], bB[8];

#define ISSUE(buf, base_off)                                                  \
        _Pragma("unroll")                                                     \
        for (int j = 0; j < 8; ++j)                                           \
            buf[j] = *reinterpret_cast<const float2*>(xw + (base_off) + j * T_STEPS);

#define CONSUME(buf, c_off, ax, ay)                                           \
        _Pragma("unroll")                                                     \
        for (int j = 0; j < 8; ++j) {                                         \
            ax = fmaf(Wr[(c_off) + j], buf[j].x, ax);                         \
            ay = fmaf(Wr[(c_off) + j], buf[j].y, ay);                         \
        }

        float n0x = 0.f, n0y = 0.f, n1x = 0.f, n1y = 0.f;

        ISSUE(bA, 0)                                   // n0 c0..7
        ISSUE(bB, 8 * T_STEPS)                         // n0 c8..15
        CONSUME(bA, 0, n0x, n0y)
        ISSUE(bA, 16 * T_STEPS)                        // n0 c16..23
        CONSUME(bB, 8, n0x, n0y)
        ISSUE(bB, 24 * T_STEPS)                        // n0 c24..31
        CONSUME(bA, 16, n0x, n0y)
        ISSUE(bA, NSTR)                                // n1 c0..7
        CONSUME(bB, 24, n0x, n0y)
        s_in[wv * NPW + 0][2 * lane]     = n0x;
        s_in[wv * NPW + 0][2 * lane + 1] = n0y;
        ISSUE(bB, NSTR + 8 * T_STEPS)                  // n1 c8..15
        CONSUME(bA, 0, n1x, n1y)
        ISSUE(bA, NSTR + 16 * T_STEPS)                 // n1 c16..23
        CONSUME(bB, 8, n1x, n1y)
        ISSUE(bB, NSTR + 24 * T_STEPS)                 // n1 c24..31
        CONSUME(bA, 16, n1x, n1y)
        CONSUME(bB, 24, n1x, n1y)
        s_in[wv * NPW + 1][2 * lane]     = n1x;
        s_in[wv * NPW + 1][2 * lane + 1] = n1y;
#undef ISSUE
#undef CONSUME
    }
    __syncthreads();

    // ---- Phase B: LIF scan, sequential in t (nonlinear reset -> serial).
    // Lanes 0..1 of each wave scan the wave's 2 neurons.
    if (lane < NPW) {
        const int nl = wv * NPW + lane;
        const float A = 0.9048374180359595f;   // exp(-1/10) rounded to f32
        const float B = 0.0951625819640404f;   // 1 - alpha
        float v = 0.f;
        #pragma unroll 4
        for (int t = 0; t < T_STEPS; ++t) {
            v = fmaf(A, v, B * s_in[nl][t]);
            const float sp = (v >= 1.0f) ? 1.0f : 0.0f;
            v -= sp;                           // membrane subtract (THR = 1)
            s_sp[nl][t] = sp;
        }
    }
    __syncthreads();

    // ---- Phase C: coalesced write of the block's contiguous output slice.
    float* op = out + (size_t)n_base * T_STEPS;
    for (int k = tid; k < NPB * T_STEPS; k += 256) {
        op[k] = s_sp[k / T_STEPS][k % T_STEPS];
    }
}

extern "C" void kernel_launch(void* const* d_in, const int* in_sizes, int n_in,
                              void* d_out, int out_size, void* d_ws, size_t ws_size,
                              hipStream_t stream) {
    const float* x = (const float*)d_in[0];
    const float* W = (const float*)d_in[1];
    float* out = (float*)d_out;

    const int N = in_sizes[0] / (CHW * T_STEPS);   // 16384
    const int grid = N / NPB;                      // 2048 blocks = 1 round at 8/CU
    exodus_fused<<<grid, 256, 0, stream>>>(x, W, out);
}